// Round 1
// baseline (750.995 us; speedup 1.0000x reference)
//
#include <hip/hip_runtime.h>

// Quantizer: N=65536 rows, D=512, V=512 codes, all fp32.
// dist[n,v] = -2*dot(x[n], w[v]) + c[v], c[v] = sum_i w[i][v]^2 (column sums!)
// out[n,:] = w[argmin_v dist]. Compare via argmax of (dot - 0.5c), which is
// rounding-equivalent to np's fl(-2*dot + c) comparison (x2 scaling exact).

#define DIM   512
#define VOCAB 512

// ---- prep: c[v] = sum_i w[i][v]^2 (fp64 accum for accuracy) ----
__global__ void colsumsq_kernel(const float* __restrict__ w, float* __restrict__ c) {
    const int v = blockIdx.x * 256 + threadIdx.x;   // grid 2 x 256 = 512
    double s = 0.0;
    for (int i = 0; i < DIM; ++i) {
        const float wv = w[i * VOCAB + v];          // coalesced across v
        s += (double)wv * (double)wv;
    }
    c[v] = (float)s;
}

// ---- prep: wT[k][v] = w[v][k] ----
__global__ void transpose_kernel(const float* __restrict__ w, float* __restrict__ wT) {
    const int tid = blockIdx.x * 256 + threadIdx.x; // grid 1024 x 256 = 262144
    const int v = tid >> 9;
    const int k = tid & 511;
    wT[k * VOCAB + v] = w[tid];                     // read coalesced, write strided (L2 absorbs, tiny)
}

// ---- main: fused dist-GEMM + argmin + gather ----
// block: 256 threads, tile = 64 rows x 512 cols, K chunks of 16.
// thread micro-tile: 8 rows x 16 cols (cols strided: v = tx + 32j).
template<bool USE_WT>
__launch_bounds__(256)
__global__ void dist_argmin_gather(const float* __restrict__ x,
                                   const float* __restrict__ w,
                                   const float* __restrict__ wT,
                                   const float* __restrict__ cg,
                                   float* __restrict__ out)
{
    __shared__ __align__(16) float As[16][68];     // [k][row], pad 68 to break write conflicts
    __shared__ __align__(16) float Bs[16][VOCAB];  // [k][v], b32 reads conflict-free
    __shared__ int   idx_s[64];
    __shared__ float c_s[VOCAB];                   // only written when !USE_WT

    const int t  = threadIdx.x;
    const int tx = t & 31;       // 0..31 -> col base
    const int ty = t >> 5;       // 0..7  -> row group (8 rows)
    const long rbase = (long)blockIdx.x * 64;
    const float* xblk = x + rbase * DIM;

    if constexpr (!USE_WT) {
        // fallback when ws too small: compute c in-block (fp64 accum)
        for (int vv = t; vv < VOCAB; vv += 256) {
            double s = 0.0;
            for (int i = 0; i < DIM; ++i) {
                const float wv = w[i * VOCAB + vv];
                s += (double)wv * (double)wv;
            }
            c_s[vv] = (float)s;
        }
    }

    float acc[8][16];
    #pragma unroll
    for (int r = 0; r < 8; ++r)
        #pragma unroll
        for (int j = 0; j < 16; ++j) acc[r][j] = 0.0f;

    for (int k0 = 0; k0 < DIM; k0 += 16) {
        __syncthreads();   // protect LDS reuse (also covers c_s producer on first iter)
        // stage A: 64 rows x 16 k (1 float4/thread)
        {
            const int r  = t >> 2;
            const int kq = (t & 3) << 2;
            const float4 a4 = *(const float4*)(xblk + (long)r * DIM + k0 + kq);
            As[kq + 0][r] = a4.x; As[kq + 1][r] = a4.y;
            As[kq + 2][r] = a4.z; As[kq + 3][r] = a4.w;
        }
        // stage B: 16 k-rows x 512 v
        if constexpr (USE_WT) {
            const float4* src = (const float4*)(wT + (long)k0 * VOCAB);
            float4* dst = (float4*)(&Bs[0][0]);   // tile is contiguous in wT
            #pragma unroll
            for (int j = 0; j < 8; ++j) dst[t + 256 * j] = src[t + 256 * j];
        } else {
            #pragma unroll
            for (int vb = 0; vb < 8; ++vb) {
                const int v  = (t >> 2) + (vb << 6);
                const int kq = (t & 3) << 2;
                const float4 b4 = *(const float4*)(w + (long)v * DIM + k0 + kq);
                Bs[kq + 0][v] = b4.x; Bs[kq + 1][v] = b4.y;
                Bs[kq + 2][v] = b4.z; Bs[kq + 3][v] = b4.w;
            }
        }
        __syncthreads();

        #pragma unroll
        for (int k = 0; k < 16; ++k) {
            float a[8];
            const float4 a03 = *(const float4*)&As[k][ty * 8];
            const float4 a47 = *(const float4*)&As[k][ty * 8 + 4];
            a[0] = a03.x; a[1] = a03.y; a[2] = a03.z; a[3] = a03.w;
            a[4] = a47.x; a[5] = a47.y; a[6] = a47.z; a[7] = a47.w;
            float b[16];
            #pragma unroll
            for (int j = 0; j < 16; ++j) b[j] = Bs[k][tx + (j << 5)];
            #pragma unroll
            for (int r = 0; r < 8; ++r)
                #pragma unroll
                for (int j = 0; j < 16; ++j)
                    acc[r][j] = fmaf(a[r], b[j], acc[r][j]);
        }
    }

    // epilogue: per-row argmax of (dot - 0.5c), tie -> smallest v (np argmin-first)
    float cv[16];
    #pragma unroll
    for (int j = 0; j < 16; ++j)
        cv[j] = USE_WT ? cg[tx + (j << 5)] : c_s[tx + (j << 5)];

    #pragma unroll
    for (int r = 0; r < 8; ++r) {
        float best = acc[r][0] - 0.5f * cv[0];
        int   bv   = tx;
        #pragma unroll
        for (int j = 1; j < 16; ++j) {
            const float s = acc[r][j] - 0.5f * cv[j];
            if (s > best) { best = s; bv = tx + (j << 5); }   // strict > keeps smaller v
        }
        unsigned u = __float_as_uint(best);
        u = (u & 0x80000000u) ? ~u : (u | 0x80000000u);       // orderable-uint map
        unsigned long long key =
            ((unsigned long long)u << 32) | (unsigned)(~(unsigned)bv); // low word: bigger = smaller v
        #pragma unroll
        for (int m = 1; m <= 16; m <<= 1) {
            const unsigned long long o = __shfl_xor(key, m, 64);  // masks <=16 stay in 32-lane half
            if (o > key) key = o;
        }
        if (tx == 0) idx_s[ty * 8 + r] = (int)(~(unsigned)(key & 0xFFFFFFFFull));
    }
    __syncthreads();

    // fused gather: 64 rows x 512 floats, 2 rows / iteration
    for (int rr = 0; rr < 64; rr += 2) {
        const int row  = rr + (t >> 7);
        const int col  = (t & 127) << 2;
        const int vidx = idx_s[row];
        const float4 val = *(const float4*)(w + (long)vidx * DIM + col);
        *(float4*)(out + (rbase + row) * DIM + col) = val;
    }
}

extern "C" void kernel_launch(void* const* d_in, const int* in_sizes, int n_in,
                              void* d_out, int out_size, void* d_ws, size_t ws_size,
                              hipStream_t stream) {
    const float* x = (const float*)d_in[0];
    const float* w = (const float*)d_in[1];
    float* out = (float*)d_out;

    const int rows = in_sizes[0] / DIM;        // 65536
    const int grid = rows / 64;                // 1024

    const size_t need = (size_t)DIM * VOCAB * sizeof(float) + VOCAB * sizeof(float);
    if (ws_size >= need) {
        float* wT = (float*)d_ws;
        float* c  = wT + (size_t)DIM * VOCAB;
        transpose_kernel<<<(DIM * VOCAB) / 256, 256, 0, stream>>>(w, wT);
        colsumsq_kernel<<<VOCAB / 256, 256, 0, stream>>>(w, c);
        dist_argmin_gather<true><<<grid, 256, 0, stream>>>(x, w, wT, c, out);
    } else {
        dist_argmin_gather<false><<<grid, 256, 0, stream>>>(x, w, nullptr, nullptr, out);
    }
}